// Round 8
// baseline (172.472 us; speedup 1.0000x reference)
//
#include <hip/hip_runtime.h>
#include <math.h>

// Problem constants (from reference setup_inputs)
#define BS 64      // batch
#define F  256     // features (K of the Gram matmul)
#define M  128     // columns  (M=N of the Gram matmul)
#define MF (M * F) // u16 elements per matrix in hT
#define NBP 1056   // blocks per mat: sum_a ceil((64-a)/2)

typedef unsigned short u16;
typedef _Float16 f16x8 __attribute__((ext_vector_type(8)));
typedef float    f32x16 __attribute__((ext_vector_type(16)));

// ---------------------------------------------------------------------------
// Pre-pass: fp32 [f][m] -> fp16 GRANULE-MAJOR hT[b][f8][m][8]. (round 6:
// coalesced staging worth 107->58 us; layout verified.)
// ---------------------------------------------------------------------------
__global__ __launch_bounds__(256) void convert_f16_kernel(
    const float* __restrict__ m1, const float* __restrict__ m2,
    u16* __restrict__ hT)
{
    __shared__ float tile[64 * M];   // 32 KB
    const int mat = blockIdx.x >> 6;
    const int b   = blockIdx.x & 63;
    const int f0  = blockIdx.y * 64;
    const float* src = (mat == 0 ? m1 : m2) + (size_t)b * MF + (size_t)f0 * M;
    const int tid = threadIdx.x;

    const float4* g = (const float4*)src;
    float4* s = (float4*)tile;
    #pragma unroll
    for (int i = 0; i < 8; ++i)
        s[tid + i * 256] = g[tid + i * 256];
    __syncthreads();

    const size_t obase = ((size_t)(mat * BS + b) * 32 + (f0 >> 3)) * 1024;
    #pragma unroll
    for (int it = 0; it < 4; ++it) {
        const int idx = it * 256 + tid;
        const int f8l = idx >> 7;
        const int m   = idx & 127;
        u16 hh[8] __attribute__((aligned(16)));
        #pragma unroll
        for (int j = 0; j < 8; ++j) {
            const float x = tile[(f8l * 8 + j) * M + m];  // 2 lanes/bank: free
            const _Float16 h = (_Float16)x;               // RNE
            hh[j] = __builtin_bit_cast(u16, h);
        }
        *(uint4*)&hT[obase + (size_t)idx * 8] = *(const uint4*)hh;
    }
}

// ---------------------------------------------------------------------------
// One block per (a, b-pair): pairs (a,b1),(a,b2=b1+1) share the A-tile.
// 4 waves; wave w = (pp=w>>1, c=w&1) computes a 128x64 region of pair pp
// (acc = 8 x f32x16 = 128 AGPR, 2 waves/SIMD -- round 6's best shape; round
// 7 proved smaller tiles lose to LDS-port traffic).
// Staging: REGISTER pipeline (global->VGPR at iteration top, compute covers
// the latency, then ds_write->alt buffer, ONE barrier). This removes the
// round-6 "vmcnt(0) drains the in-flight DMA at the barrier" stall: the
// barrier now only orders LDS writes; global latency is hidden under MFMA.
// LDS: double-buffered [buf][{A,B1,B2} 8KB] = 48 KB, granule-major ==
// global layout (coalesced loads, 0 bank conflicts -- verified r6/r7).
// ---------------------------------------------------------------------------
__global__ __launch_bounds__(256, 2) void gram_hist_mfma(
    const u16* __restrict__ hT, float* __restrict__ out)
{
    __shared__ u16 lds[2 * 12288];   // 48 KB
    __shared__ float smin[4], smax[4];
    __shared__ int hist[2][8];

    const int tid  = threadIdx.x;
    const int lane = tid & 63;
    const int w    = tid >> 6;

    if (tid < 16) hist[tid >> 3][tid & 7] = 0;

    // Decode blockIdx.x -> (a, p) with per-a count ceil((64-a)/2).
    int p = blockIdx.x, a = 0;
    { int cnt = 32; while (p >= cnt) { p -= cnt; ++a; cnt = (64 - a + 1) >> 1; } }
    const int b1 = a + 2 * p;
    int b2 = b1 + 1;
    const bool b2valid = (b2 <= 63);
    if (!b2valid) b2 = b1;          // duplicate work, writes suppressed
    const int mat = blockIdx.y;

    const u16* Asrc  = hT + (size_t)(mat * BS + a)  * MF;
    const u16* B1src = hT + (size_t)(mat * BS + b1) * MF;
    const u16* B2src = hT + (size_t)(mat * BS + b2) * MF;

    // --- register staging: 6 x uint4 per thread = one 32-k chunk (24 KB) ---
    uint4 rg[6];
    auto load_regs = [&](int koff) {
        #pragma unroll
        for (int g = 0; g < 6; ++g) {
            const int idx = (g & 1) * 256 + tid;   // 0..511, lane-contiguous
            const u16* s = (g < 2 ? Asrc : (g < 4 ? B1src : B2src)) + koff + idx * 8;
            rg[g] = *(const uint4*)s;              // coalesced 16B
        }
    };
    auto write_lds = [&](int bufo) {
        #pragma unroll
        for (int g = 0; g < 6; ++g) {
            const int idx = (g & 1) * 256 + tid;
            *(uint4*)&lds[bufo + (g >> 1) * 4096 + idx * 8] = rg[g];  // ds_write_b128
        }
    };

    const int pp = w >> 1;     // which pair (0: b1, 1: b2)
    const int c  = w & 1;      // which 64-col half
    const int l31   = lane & 31;
    const int lhalf = lane >> 5;

    f32x16 acc[4][2];
    #pragma unroll
    for (int ti = 0; ti < 4; ++ti)
        #pragma unroll
        for (int u = 0; u < 2; ++u)
            #pragma unroll
            for (int r = 0; r < 16; ++r) acc[ti][u][r] = 0.0f;

    load_regs(0);
    write_lds(0);
    __syncthreads();

    for (int it = 0; it < 8; ++it) {
        const int cur = (it & 1) * 12288;
        if (it < 7) load_regs((it + 1) * 4096);   // global->VGPR, hidden by compute

        #pragma unroll
        for (int kk = 0; kk < 2; ++kk) {
            const int kb = kk * 2 + lhalf;
            f16x8 af[4], bf[2];
            #pragma unroll
            for (int t = 0; t < 4; ++t)
                af[t] = *(const f16x8*)&lds[cur + (kb * 128 + t * 32 + l31) * 8];
            #pragma unroll
            for (int t = 0; t < 2; ++t)
                bf[t] = *(const f16x8*)&lds[cur + (1 + pp) * 4096 + (kb * 128 + c * 64 + t * 32 + l31) * 8];
            #pragma unroll
            for (int ti = 0; ti < 4; ++ti)
                #pragma unroll
                for (int u = 0; u < 2; ++u)
                    acc[ti][u] = __builtin_amdgcn_mfma_f32_32x32x16_f16(af[ti], bf[u], acc[ti][u], 0, 0, 0);
        }

        if (it < 7) write_lds(cur ^ 12288);       // VGPR->LDS (alt buffer)
        __syncthreads();                          // orders LDS writes only
    }

    // ---- epilogue: pair pp owned by waves (pp,c=0),(pp,c=1) ----
    float vmin = acc[0][0][0], vmax = vmin;
    #pragma unroll
    for (int ti = 0; ti < 4; ++ti)
        #pragma unroll
        for (int u = 0; u < 2; ++u)
            #pragma unroll
            for (int r = 0; r < 16; ++r) {
                vmin = fminf(vmin, acc[ti][u][r]);
                vmax = fmaxf(vmax, acc[ti][u][r]);
            }
    #pragma unroll
    for (int off = 1; off < 64; off <<= 1) {
        vmin = fminf(vmin, __shfl_xor(vmin, off, 64));
        vmax = fmaxf(vmax, __shfl_xor(vmax, off, 64));
    }
    if (lane == 0) { smin[w] = vmin; smax[w] = vmax; }
    __syncthreads();
    const float pmn = fminf(smin[pp * 2], smin[pp * 2 + 1]);
    const float pmx = fmaxf(smax[pp * 2], smax[pp * 2 + 1]);
    const float denom = (pmx > pmn) ? (pmx - pmn) : 1.0f;
    const float scale = 8.0f / denom;
    const float bias  = -pmn * scale;

    // per-thread packed histogram: 128 values -> 8-bit fields (<=128/bin)
    unsigned w0 = 0, w1 = 0;
    #pragma unroll
    for (int ti = 0; ti < 4; ++ti)
        #pragma unroll
        for (int u = 0; u < 2; ++u)
            #pragma unroll
            for (int r = 0; r < 16; ++r) {
                const float t = fmaf(acc[ti][u][r], scale, bias);
                int k = (int)t;          // t >= -eps; trunc == floor
                k = k > 7 ? 7 : k;
                const unsigned inc = 1u << ((k & 3) * 8);
                if (k < 4) w0 += inc; else w1 += inc;
            }
    unsigned e0 = (w0 & 0xFFu)         | (((w0 >> 8)  & 0xFFu) << 16);
    unsigned e1 = ((w0 >> 16) & 0xFFu) | (((w0 >> 24) & 0xFFu) << 16);
    unsigned e2 = (w1 & 0xFFu)         | (((w1 >> 8)  & 0xFFu) << 16);
    unsigned e3 = ((w1 >> 16) & 0xFFu) | (((w1 >> 24) & 0xFFu) << 16);
    #pragma unroll
    for (int off = 32; off > 0; off >>= 1) {
        e0 += __shfl_down(e0, off, 64);
        e1 += __shfl_down(e1, off, 64);
        e2 += __shfl_down(e2, off, 64);
        e3 += __shfl_down(e3, off, 64);
    }
    if (lane == 0) {
        atomicAdd(&hist[pp][0], (int)(e0 & 0xFFFFu)); atomicAdd(&hist[pp][1], (int)(e0 >> 16));
        atomicAdd(&hist[pp][2], (int)(e1 & 0xFFFFu)); atomicAdd(&hist[pp][3], (int)(e1 >> 16));
        atomicAdd(&hist[pp][4], (int)(e2 & 0xFFFFu)); atomicAdd(&hist[pp][5], (int)(e2 >> 16));
        atomicAdd(&hist[pp][6], (int)(e3 & 0xFFFFu)); atomicAdd(&hist[pp][7], (int)(e3 >> 16));
    }
    __syncthreads();

    // one wave per pair normalizes and writes both symmetric rows
    const int B = (pp == 0) ? b1 : b2;
    const bool valid = (pp == 0) || b2valid;
    if (valid && c == 0 && lane < 8) {
        float ss = 0.0f;
        #pragma unroll
        for (int k = 0; k < 8; ++k) {
            const float cc = (float)hist[pp][k];
            ss += cc * cc;
        }
        const float nrm = fmaxf(sqrtf(ss), 1e-12f);
        const float v = (float)hist[pp][lane] / nrm;
        out[((size_t)a * BS + B) * 16 + mat * 8 + lane] = v;
        if (a != B)
            out[((size_t)B * BS + a) * 16 + mat * 8 + lane] = v;
    }
}

extern "C" void kernel_launch(void* const* d_in, const int* in_sizes, int n_in,
                              void* d_out, int out_size, void* d_ws, size_t ws_size,
                              hipStream_t stream) {
    const float* m1 = (const float*)d_in[0];
    const float* m2 = (const float*)d_in[1];
    float* out = (float*)d_out;

    // Workspace: granule-major fp16 array, 2*64*128*256 u16 = 8.39 MB.
    u16* hT = (u16*)d_ws;

    convert_f16_kernel<<<dim3(128, 4), 256, 0, stream>>>(m1, m2, hT);
    gram_hist_mfma<<<dim3(NBP, 2), 256, 0, stream>>>(hT, out);
}

// Round 9
// 117.770 us; speedup vs baseline: 1.4645x; 1.4645x over previous
//
#include <hip/hip_runtime.h>
#include <math.h>

// Problem constants (from reference setup_inputs)
#define BS 64      // batch
#define F  256     // features (K of the Gram matmul)
#define M  128     // columns  (M=N of the Gram matmul)
#define MF (M * F) // u16 elements per matrix in hT
#define NBP 1056   // blocks per mat: sum_a ceil((64-a)/2)

typedef unsigned short u16;
typedef _Float16 f16x8 __attribute__((ext_vector_type(8)));
typedef float    f32x16 __attribute__((ext_vector_type(16)));

// ---------------------------------------------------------------------------
// Pre-pass: fp32 [f][m] -> fp16 GRANULE-MAJOR hT[b][f8][m][8]. (round 6:
// coalesced staging worth 107->58 us; layout verified.)
// ---------------------------------------------------------------------------
__global__ __launch_bounds__(256) void convert_f16_kernel(
    const float* __restrict__ m1, const float* __restrict__ m2,
    u16* __restrict__ hT)
{
    __shared__ float tile[64 * M];   // 32 KB
    const int mat = blockIdx.x >> 6;
    const int b   = blockIdx.x & 63;
    const int f0  = blockIdx.y * 64;
    const float* src = (mat == 0 ? m1 : m2) + (size_t)b * MF + (size_t)f0 * M;
    const int tid = threadIdx.x;

    const float4* g = (const float4*)src;
    float4* s = (float4*)tile;
    #pragma unroll
    for (int i = 0; i < 8; ++i)
        s[tid + i * 256] = g[tid + i * 256];
    __syncthreads();

    const size_t obase = ((size_t)(mat * BS + b) * 32 + (f0 >> 3)) * 1024;
    #pragma unroll
    for (int it = 0; it < 4; ++it) {
        const int idx = it * 256 + tid;
        const int f8l = idx >> 7;
        const int m   = idx & 127;
        u16 hh[8] __attribute__((aligned(16)));
        #pragma unroll
        for (int j = 0; j < 8; ++j) {
            const float x = tile[(f8l * 8 + j) * M + m];  // 2 lanes/bank: free
            const _Float16 h = (_Float16)x;               // RNE
            hh[j] = __builtin_bit_cast(u16, h);
        }
        *(uint4*)&hT[obase + (size_t)idx * 8] = *(const uint4*)hh;
    }
}

// ---------------------------------------------------------------------------
// One block per (a, b-pair): pairs (a,b1),(a,b2=b1+1) share the A-tile.
// 4 waves; wave w = (pp=w>>1, c=w&1) computes a 128x64 region of pair pp
// (acc = 8 x f32x16 = 128 AGPR, 2 waves/SIMD -- round 6's best shape).
// Staging: REGISTER pipeline -- global->VGPR at iteration top, MFMA phase
// covers the load latency, ds_write->alt buffer at phase end, ONE barrier
// that only orders LDS writes (no vmcnt(0)-drains-the-DMA stall).
// ROUND-8 BUG FIXED: staging regs are six NAMED uint4 locals in straight-line
// code. Round 8 passed a local array through [&] lambdas -> address taken ->
// scratch demotion -> 175 MB of HBM scratch traffic (WRITE_SIZE counter).
// Budget: 128 AGPR + ~115 VGPR = 243 < 256/wave at 2 waves/SIMD.
// ---------------------------------------------------------------------------
__global__ __launch_bounds__(256, 2) void gram_hist_mfma(
    const u16* __restrict__ hT, float* __restrict__ out)
{
    __shared__ u16 lds[2 * 12288];   // 48 KB: [buf][{A,B1,B2} 8KB each]
    __shared__ float smin[4], smax[4];
    __shared__ int hist[2][8];

    const int tid  = threadIdx.x;
    const int lane = tid & 63;
    const int w    = tid >> 6;

    if (tid < 16) hist[tid >> 3][tid & 7] = 0;

    // Decode blockIdx.x -> (a, p) with per-a count ceil((64-a)/2).
    int p = blockIdx.x, a = 0;
    { int cnt = 32; while (p >= cnt) { p -= cnt; ++a; cnt = (64 - a + 1) >> 1; } }
    const int b1 = a + 2 * p;
    int b2 = b1 + 1;
    const bool b2valid = (b2 <= 63);
    if (!b2valid) b2 = b1;          // duplicate work, writes suppressed
    const int mat = blockIdx.y;

    // Per-thread staging source pointers (advance by 4096 u16 per chunk).
    const u16* pa = hT + (size_t)(mat * BS + a)  * MF + tid * 8;
    const u16* pb1 = hT + (size_t)(mat * BS + b1) * MF + tid * 8;
    const u16* pb2 = hT + (size_t)(mat * BS + b2) * MF + tid * 8;

    const int pp = w >> 1;     // which pair (0: b1, 1: b2)
    const int c  = w & 1;      // which 64-col half
    const int l31   = lane & 31;
    const int lhalf = lane >> 5;

    // LDS dest offsets (u16 units) for this thread's 6 granules.
    const int d0 = tid * 8;            // A, first 256 granules
    const int d1 = (256 + tid) * 8;    // A, second
    // B1 at +4096, B2 at +8192.

    f32x16 acc[4][2];
    #pragma unroll
    for (int ti = 0; ti < 4; ++ti)
        #pragma unroll
        for (int u = 0; u < 2; ++u)
            #pragma unroll
            for (int r = 0; r < 16; ++r) acc[ti][u][r] = 0.0f;

    // ---- prologue: load + write chunk 0 ----
    uint4 r0 = *(const uint4*)(pa);
    uint4 r1 = *(const uint4*)(pa + 2048);
    uint4 r2 = *(const uint4*)(pb1);
    uint4 r3 = *(const uint4*)(pb1 + 2048);
    uint4 r4 = *(const uint4*)(pb2);
    uint4 r5 = *(const uint4*)(pb2 + 2048);
    *(uint4*)&lds[d0]         = r0;
    *(uint4*)&lds[d1]         = r1;
    *(uint4*)&lds[4096 + d0]  = r2;
    *(uint4*)&lds[4096 + d1]  = r3;
    *(uint4*)&lds[8192 + d0]  = r4;
    *(uint4*)&lds[8192 + d1]  = r5;
    __syncthreads();

    for (int it = 0; it < 8; ++it) {
        const int cur = (it & 1) * 12288;
        const int alt = cur ^ 12288;

        if (it < 7) {   // global->VGPR for chunk it+1 (latency hidden by MFMA)
            const int koff = (it + 1) * 4096;
            r0 = *(const uint4*)(pa  + koff);
            r1 = *(const uint4*)(pa  + koff + 2048);
            r2 = *(const uint4*)(pb1 + koff);
            r3 = *(const uint4*)(pb1 + koff + 2048);
            r4 = *(const uint4*)(pb2 + koff);
            r5 = *(const uint4*)(pb2 + koff + 2048);
        }

        #pragma unroll
        for (int kk = 0; kk < 2; ++kk) {
            const int kb = kk * 2 + lhalf;
            f16x8 af[4], bf[2];
            #pragma unroll
            for (int t = 0; t < 4; ++t)
                af[t] = *(const f16x8*)&lds[cur + (kb * 128 + t * 32 + l31) * 8];
            #pragma unroll
            for (int t = 0; t < 2; ++t)
                bf[t] = *(const f16x8*)&lds[cur + (1 + pp) * 4096 + (kb * 128 + c * 64 + t * 32 + l31) * 8];
            #pragma unroll
            for (int ti = 0; ti < 4; ++ti)
                #pragma unroll
                for (int u = 0; u < 2; ++u)
                    acc[ti][u] = __builtin_amdgcn_mfma_f32_32x32x16_f16(af[ti], bf[u], acc[ti][u], 0, 0, 0);
        }

        if (it < 7) {   // VGPR->LDS (alt buffer); loads have landed by now
            *(uint4*)&lds[alt + d0]        = r0;
            *(uint4*)&lds[alt + d1]        = r1;
            *(uint4*)&lds[alt + 4096 + d0] = r2;
            *(uint4*)&lds[alt + 4096 + d1] = r3;
            *(uint4*)&lds[alt + 8192 + d0] = r4;
            *(uint4*)&lds[alt + 8192 + d1] = r5;
        }
        __syncthreads();   // orders LDS writes only
    }

    // ---- epilogue: pair pp owned by waves (pp,c=0),(pp,c=1) ----
    float vmin = acc[0][0][0], vmax = vmin;
    #pragma unroll
    for (int ti = 0; ti < 4; ++ti)
        #pragma unroll
        for (int u = 0; u < 2; ++u)
            #pragma unroll
            for (int r = 0; r < 16; ++r) {
                vmin = fminf(vmin, acc[ti][u][r]);
                vmax = fmaxf(vmax, acc[ti][u][r]);
            }
    #pragma unroll
    for (int off = 1; off < 64; off <<= 1) {
        vmin = fminf(vmin, __shfl_xor(vmin, off, 64));
        vmax = fmaxf(vmax, __shfl_xor(vmax, off, 64));
    }
    if (lane == 0) { smin[w] = vmin; smax[w] = vmax; }
    __syncthreads();
    const float pmn = fminf(smin[pp * 2], smin[pp * 2 + 1]);
    const float pmx = fmaxf(smax[pp * 2], smax[pp * 2 + 1]);
    const float denom = (pmx > pmn) ? (pmx - pmn) : 1.0f;
    const float scale = 8.0f / denom;
    const float bias  = -pmn * scale;

    // per-thread packed histogram: 128 values -> 8-bit fields (<=128/bin)
    unsigned w0 = 0, w1 = 0;
    #pragma unroll
    for (int ti = 0; ti < 4; ++ti)
        #pragma unroll
        for (int u = 0; u < 2; ++u)
            #pragma unroll
            for (int r = 0; r < 16; ++r) {
                const float t = fmaf(acc[ti][u][r], scale, bias);
                int k = (int)t;          // t >= -eps; trunc == floor
                k = k > 7 ? 7 : k;
                const unsigned inc = 1u << ((k & 3) * 8);
                if (k < 4) w0 += inc; else w1 += inc;
            }
    unsigned e0 = (w0 & 0xFFu)         | (((w0 >> 8)  & 0xFFu) << 16);
    unsigned e1 = ((w0 >> 16) & 0xFFu) | (((w0 >> 24) & 0xFFu) << 16);
    unsigned e2 = (w1 & 0xFFu)         | (((w1 >> 8)  & 0xFFu) << 16);
    unsigned e3 = ((w1 >> 16) & 0xFFu) | (((w1 >> 24) & 0xFFu) << 16);
    #pragma unroll
    for (int off = 32; off > 0; off >>= 1) {
        e0 += __shfl_down(e0, off, 64);
        e1 += __shfl_down(e1, off, 64);
        e2 += __shfl_down(e2, off, 64);
        e3 += __shfl_down(e3, off, 64);
    }
    if (lane == 0) {
        atomicAdd(&hist[pp][0], (int)(e0 & 0xFFFFu)); atomicAdd(&hist[pp][1], (int)(e0 >> 16));
        atomicAdd(&hist[pp][2], (int)(e1 & 0xFFFFu)); atomicAdd(&hist[pp][3], (int)(e1 >> 16));
        atomicAdd(&hist[pp][4], (int)(e2 & 0xFFFFu)); atomicAdd(&hist[pp][5], (int)(e2 >> 16));
        atomicAdd(&hist[pp][6], (int)(e3 & 0xFFFFu)); atomicAdd(&hist[pp][7], (int)(e3 >> 16));
    }
    __syncthreads();

    // one wave per pair normalizes and writes both symmetric rows
    const int B = (pp == 0) ? b1 : b2;
    const bool valid = (pp == 0) || b2valid;
    if (valid && c == 0 && lane < 8) {
        float ss = 0.0f;
        #pragma unroll
        for (int k = 0; k < 8; ++k) {
            const float cc = (float)hist[pp][k];
            ss += cc * cc;
        }
        const float nrm = fmaxf(sqrtf(ss), 1e-12f);
        const float v = (float)hist[pp][lane] / nrm;
        out[((size_t)a * BS + B) * 16 + mat * 8 + lane] = v;
        if (a != B)
            out[((size_t)B * BS + a) * 16 + mat * 8 + lane] = v;
    }
}

extern "C" void kernel_launch(void* const* d_in, const int* in_sizes, int n_in,
                              void* d_out, int out_size, void* d_ws, size_t ws_size,
                              hipStream_t stream) {
    const float* m1 = (const float*)d_in[0];
    const float* m2 = (const float*)d_in[1];
    float* out = (float*)d_out;

    // Workspace: granule-major fp16 array, 2*64*128*256 u16 = 8.39 MB.
    u16* hT = (u16*)d_ws;

    convert_f16_kernel<<<dim3(128, 4), 256, 0, stream>>>(m1, m2, hT);
    gram_hist_mfma<<<dim3(NBP, 2), 256, 0, stream>>>(hT, out);
}